// Round 2
// baseline (315.331 us; speedup 1.0000x reference)
//
#include <hip/hip_runtime.h>
#include <math.h>

// Fixed shape: N=8192 rows, D=4096 cols, fp32 in, fp32 scalar out.
#define N_ROWS 8192
#define D_COLS 4096
#define MARGIN 5.0f
#define PAIR_BLOCKS 1024

// ---------------------------------------------------------------------------
// dist: one WAVE per row (no LDS, no __syncthreads). 4 rows per 256-block.
// Each lane: 16 float4 loads per array = 512 B, 32 outstanding dwordx4 for MLP.
// dp[i] = (t==1) ? d : -inf ; dn[i] = (t==0) ? d : +inf  (self-masking hinge).
// Block 0 thread 0 also zeroes the pair-kernel accumulators (ws is 0xAA-poisoned);
// stream order guarantees visibility before pair_kernel starts.
__global__ __launch_bounds__(256) void dist_kernel(
    const float* __restrict__ rx, const float* __restrict__ x,
    const int* __restrict__ tgt, float* __restrict__ dp, float* __restrict__ dn,
    double* __restrict__ sum, int* __restrict__ ticket, int* __restrict__ npos) {
  if (blockIdx.x == 0 && threadIdx.x == 0) { *sum = 0.0; *ticket = 0; *npos = 0; }
  const int lane = threadIdx.x & 63;
  const int row  = blockIdx.x * 4 + (threadIdx.x >> 6);
  const float4* a = reinterpret_cast<const float4*>(rx) + (size_t)row * (D_COLS / 4);
  const float4* b = reinterpret_cast<const float4*>(x)  + (size_t)row * (D_COLS / 4);
  float s = 0.f;
#pragma unroll
  for (int k = 0; k < D_COLS / 4 / 64; ++k) {   // 16 float4 per lane per array
    float4 va = a[lane + k * 64];
    float4 vb = b[lane + k * 64];
    float d0 = va.x - vb.x, d1 = va.y - vb.y, d2 = va.z - vb.z, d3 = va.w - vb.w;
    s = fmaf(d0, d0, s); s = fmaf(d1, d1, s);
    s = fmaf(d2, d2, s); s = fmaf(d3, d3, s);
  }
#pragma unroll
  for (int off = 32; off; off >>= 1) s += __shfl_down(s, off, 64);  // wave=64
  if (lane == 0) {
    float dd = sqrtf(s) + 0.001f;
    int t = tgt[row];
    dp[row] = (t == 1) ? dd : -INFINITY;
    dn[row] = (t == 0) ? dd : INFINITY;
  }
}

// ---------------------------------------------------------------------------
// pairs + finalize: each thread caches 32 dn values in registers; blocks stride
// over i. Thread 0 counts positive rows in its stripe. Per-block: one f64
// atomicAdd (sum), one i32 atomicAdd (npos), then a ticket; the last block
// reads the totals (fence + atomic-read) and writes the mean to d_out.
__global__ __launch_bounds__(256) void pair_kernel(
    const float* __restrict__ dp, const float* __restrict__ dn,
    double* __restrict__ sum, int* __restrict__ ticket, int* __restrict__ npos,
    float* __restrict__ out) {
  float r[N_ROWS / 256];
#pragma unroll
  for (int k = 0; k < N_ROWS / 256; ++k) r[k] = dn[threadIdx.x + k * 256];
  float acc = 0.f;
  int cnt = 0;
  for (int i = blockIdx.x; i < N_ROWS; i += PAIR_BLOCKS) {
    float dpi = dp[i];                 // uniform across block
    if (dpi == -INFINITY) continue;    // wave-uniform skip of non-pos rows
    ++cnt;
    float dpi5 = dpi + MARGIN;
#pragma unroll
    for (int k = 0; k < N_ROWS / 256; ++k) acc += fmaxf(dpi5 - r[k], 0.f);
  }
#pragma unroll
  for (int off = 32; off; off >>= 1) acc += __shfl_down(acc, off, 64);
  __shared__ float ws[4];
  const int lane = threadIdx.x & 63, wid = threadIdx.x >> 6;
  if (lane == 0) ws[wid] = acc;
  __syncthreads();
  if (threadIdx.x == 0) {
    atomicAdd(sum, (double)(ws[0] + ws[1] + ws[2] + ws[3]));
    atomicAdd(npos, cnt);
    __threadfence();
    int t = atomicAdd(ticket, 1);
    if (t == PAIR_BLOCKS - 1) {        // last block: all adds are visible
      double s = atomicAdd(sum, 0.0);
      long long np = (long long)atomicAdd(npos, 0);
      long long c = np * (long long)(N_ROWS - np);
      out[0] = (float)(s / (double)c);
    }
  }
}

// ---------------------------------------------------------------------------
extern "C" void kernel_launch(void* const* d_in, const int* in_sizes, int n_in,
                              void* d_out, int out_size, void* d_ws, size_t ws_size,
                              hipStream_t stream) {
  const float* rx  = (const float*)d_in[0];
  const float* x   = (const float*)d_in[1];
  const int*   tgt = (const int*)d_in[2];
  float* out = (float*)d_out;

  // ws layout: dp[8192] f32 | dn[8192] f32 | sum f64 | ticket i32 | npos i32
  float*  dp     = (float*)d_ws;
  float*  dn     = dp + N_ROWS;
  double* sum    = (double*)(dn + N_ROWS);
  int*    ticket = (int*)(sum + 1);
  int*    npos   = ticket + 1;

  dist_kernel<<<N_ROWS / 4, 256, 0, stream>>>(rx, x, tgt, dp, dn, sum, ticket, npos);
  pair_kernel<<<PAIR_BLOCKS, 256, 0, stream>>>(dp, dn, sum, ticket, npos, out);
}

// Round 3
// 290.841 us; speedup vs baseline: 1.0842x; 1.0842x over previous
//
#include <hip/hip_runtime.h>
#include <math.h>

// Fixed shape: N=8192 rows, D=4096 cols, fp32 in, fp32 scalar out.
#define N_ROWS 8192
#define D_COLS 4096
#define MARGIN 5.0f
#define PAIR_BLOCKS 256

// ---------------------------------------------------------------------------
// dist: one WAVE per row, 4 rows per 256-block, grid 2048.
// Explicit memory-level parallelism: stage 8 float4-pairs (16 independent
// global_load_dwordx4) in registers before any FMA. Outer loop kept rolled
// (unroll 1) so payload stays ~64 VGPRs -> ~5 waves/SIMD occupancy.
// dp[i] = (t==1) ? d : -inf ; dn[i] = (t==0) ? d : +inf  (self-masking hinge).
__global__ __launch_bounds__(256) void dist_kernel(
    const float* __restrict__ rx, const float* __restrict__ x,
    const int* __restrict__ tgt, float* __restrict__ dp, float* __restrict__ dn) {
  const int lane = threadIdx.x & 63;
  const int row  = blockIdx.x * 4 + (threadIdx.x >> 6);
  const float4* a = reinterpret_cast<const float4*>(rx) + (size_t)row * (D_COLS / 4);
  const float4* b = reinterpret_cast<const float4*>(x)  + (size_t)row * (D_COLS / 4);
  float s0 = 0.f, s1 = 0.f;
#pragma unroll 1
  for (int c = 0; c < D_COLS / 4 / 64 / 8; ++c) {   // 2 outer iters
    float4 va[8], vb[8];
#pragma unroll
    for (int u = 0; u < 8; ++u) va[u] = a[lane + (c * 8 + u) * 64];
#pragma unroll
    for (int u = 0; u < 8; ++u) vb[u] = b[lane + (c * 8 + u) * 64];
#pragma unroll
    for (int u = 0; u < 8; ++u) {
      float d0 = va[u].x - vb[u].x, d1 = va[u].y - vb[u].y;
      float d2 = va[u].z - vb[u].z, d3 = va[u].w - vb[u].w;
      s0 = fmaf(d0, d0, s0); s1 = fmaf(d1, d1, s1);
      s0 = fmaf(d2, d2, s0); s1 = fmaf(d3, d3, s1);
    }
  }
  float s = s0 + s1;
#pragma unroll
  for (int off = 32; off; off >>= 1) s += __shfl_down(s, off, 64);  // wave=64
  if (lane == 0) {
    float dd = sqrtf(s) + 0.001f;
    int t = tgt[row];
    dp[row] = (t == 1) ? dd : -INFINITY;
    dn[row] = (t == 0) ? dd : INFINITY;
  }
}

// ---------------------------------------------------------------------------
// pairs: NO atomics, NO fences. 256 blocks; each thread caches 32 dn values in
// registers; block strides over i (32 rows each); one f32 partial per block.
// The +-inf encoding zeroes masked pairs (no NaN possible: only -inf-(+inf)).
__global__ __launch_bounds__(256) void pair_kernel(
    const float* __restrict__ dp, const float* __restrict__ dn,
    float* __restrict__ partial) {
  float r[N_ROWS / 256];
#pragma unroll
  for (int k = 0; k < N_ROWS / 256; ++k) r[k] = dn[threadIdx.x + k * 256];
  float acc = 0.f;
#pragma unroll 1
  for (int i = blockIdx.x; i < N_ROWS; i += PAIR_BLOCKS) {
    float dpi = dp[i];                 // uniform across block
    if (dpi == -INFINITY) continue;    // wave-uniform skip of non-pos rows
    float dpi5 = dpi + MARGIN;
#pragma unroll
    for (int k = 0; k < N_ROWS / 256; ++k) acc += fmaxf(dpi5 - r[k], 0.f);
  }
#pragma unroll
  for (int off = 32; off; off >>= 1) acc += __shfl_down(acc, off, 64);
  __shared__ float ws[4];
  const int lane = threadIdx.x & 63, wid = threadIdx.x >> 6;
  if (lane == 0) ws[wid] = acc;
  __syncthreads();
  if (threadIdx.x == 0) partial[blockIdx.x] = ws[0] + ws[1] + ws[2] + ws[3];
}

// ---------------------------------------------------------------------------
// finalize: one block. Reduce 256 partials (in double), count positives from
// dp (dp[i] != -inf), write mean.
__global__ __launch_bounds__(256) void final_kernel(
    const float* __restrict__ dp, const float* __restrict__ partial,
    float* __restrict__ out) {
  double s = (double)partial[threadIdx.x];
  int c = 0;
#pragma unroll
  for (int k = 0; k < N_ROWS / 256; ++k)
    c += (dp[threadIdx.x + k * 256] != -INFINITY);
#pragma unroll
  for (int off = 32; off; off >>= 1) {
    s += __shfl_down(s, off, 64);
    c += __shfl_down(c, off, 64);
  }
  __shared__ double sws[4];
  __shared__ int cws[4];
  const int lane = threadIdx.x & 63, wid = threadIdx.x >> 6;
  if (lane == 0) { sws[wid] = s; cws[wid] = c; }
  __syncthreads();
  if (threadIdx.x == 0) {
    double tot = sws[0] + sws[1] + sws[2] + sws[3];
    long long np = cws[0] + cws[1] + cws[2] + cws[3];
    long long cnt = np * (long long)(N_ROWS - np);
    out[0] = (float)(tot / (double)cnt);
  }
}

// ---------------------------------------------------------------------------
extern "C" void kernel_launch(void* const* d_in, const int* in_sizes, int n_in,
                              void* d_out, int out_size, void* d_ws, size_t ws_size,
                              hipStream_t stream) {
  const float* rx  = (const float*)d_in[0];
  const float* x   = (const float*)d_in[1];
  const int*   tgt = (const int*)d_in[2];
  float* out = (float*)d_out;

  // ws layout: dp[8192] f32 | dn[8192] f32 | partial[256] f32
  float* dp      = (float*)d_ws;
  float* dn      = dp + N_ROWS;
  float* partial = dn + N_ROWS;

  dist_kernel<<<N_ROWS / 4, 256, 0, stream>>>(rx, x, tgt, dp, dn);
  pair_kernel<<<PAIR_BLOCKS, 256, 0, stream>>>(dp, dn, partial);
  final_kernel<<<1, 256, 0, stream>>>(dp, partial, out);
}

// Round 4
// 287.691 us; speedup vs baseline: 1.0961x; 1.0109x over previous
//
#include <hip/hip_runtime.h>
#include <math.h>

// Fixed shape: N=8192 rows, D=4096 cols, fp32 in, fp32 scalar out.
#define N_ROWS 8192
#define D_COLS 4096
#define MARGIN 5.0f
#define PAIR_BLOCKS 256

// ---------------------------------------------------------------------------
// dist: one WAVE per row, 4 rows per 256-block, grid 2048 (= 8 blocks/CU,
// 32 waves/CU). Software-pipelined: 4 chunks of 8 loads (4 float4 from each
// input); chunk c+1's loads are issued BEFORE chunk c's FMAs, and
// sched_barrier(0) pins that order so the register-minimizing scheduler
// cannot sink the loads into their uses (R3's staging collapsed to 32 VGPRs
// and ~2 outstanding loads/wave -> latency-bound at 2.7 TB/s).
// dp[i] = (t==1) ? d : -inf ; dn[i] = (t==0) ? d : +inf  (self-masking hinge).
__global__ __launch_bounds__(256) void dist_kernel(
    const float* __restrict__ rx, const float* __restrict__ x,
    const int* __restrict__ tgt, float* __restrict__ dp, float* __restrict__ dn) {
  const int lane = threadIdx.x & 63;
  const int row  = blockIdx.x * 4 + (threadIdx.x >> 6);
  const float4* a = reinterpret_cast<const float4*>(rx) + (size_t)row * (D_COLS / 4);
  const float4* b = reinterpret_cast<const float4*>(x)  + (size_t)row * (D_COLS / 4);

  float4 pa[4], pb[4];                       // prefetch registers (in flight)
#pragma unroll
  for (int u = 0; u < 4; ++u) pa[u] = a[lane + u * 64];
#pragma unroll
  for (int u = 0; u < 4; ++u) pb[u] = b[lane + u * 64];
  __builtin_amdgcn_sched_barrier(0);         // prologue loads issued first

  float s0 = 0.f, s1 = 0.f, s2 = 0.f, s3 = 0.f;
#pragma unroll
  for (int c = 0; c < 4; ++c) {              // 4 chunks x 4 float4/lane/input
    float4 ca[4], cb[4];
#pragma unroll
    for (int u = 0; u < 4; ++u) { ca[u] = pa[u]; cb[u] = pb[u]; }
    if (c < 3) {
#pragma unroll
      for (int u = 0; u < 4; ++u) pa[u] = a[lane + ((c + 1) * 4 + u) * 64];
#pragma unroll
      for (int u = 0; u < 4; ++u) pb[u] = b[lane + ((c + 1) * 4 + u) * 64];
    }
    __builtin_amdgcn_sched_barrier(0);       // next chunk's loads stay ABOVE
#pragma unroll
    for (int u = 0; u < 4; ++u) {            // 4 independent acc chains
      float d0 = ca[u].x - cb[u].x, d1 = ca[u].y - cb[u].y;
      float d2 = ca[u].z - cb[u].z, d3 = ca[u].w - cb[u].w;
      s0 = fmaf(d0, d0, s0); s1 = fmaf(d1, d1, s1);
      s2 = fmaf(d2, d2, s2); s3 = fmaf(d3, d3, s3);
    }
    __builtin_amdgcn_sched_barrier(0);       // FMAs stay ahead of next prefetch
  }
  float s = (s0 + s1) + (s2 + s3);
#pragma unroll
  for (int off = 32; off; off >>= 1) s += __shfl_down(s, off, 64);  // wave=64
  if (lane == 0) {
    float dd = sqrtf(s) + 0.001f;
    int t = tgt[row];
    dp[row] = (t == 1) ? dd : -INFINITY;
    dn[row] = (t == 0) ? dd : INFINITY;
  }
}

// ---------------------------------------------------------------------------
// pairs: NO atomics, NO fences. 256 blocks; each thread caches 32 dn values in
// registers; block strides over i (32 rows each); one f32 partial per block.
// The +-inf encoding zeroes masked pairs (no NaN possible: only -inf-(+inf)).
__global__ __launch_bounds__(256) void pair_kernel(
    const float* __restrict__ dp, const float* __restrict__ dn,
    float* __restrict__ partial) {
  float r[N_ROWS / 256];
#pragma unroll
  for (int k = 0; k < N_ROWS / 256; ++k) r[k] = dn[threadIdx.x + k * 256];
  float acc = 0.f;
#pragma unroll 1
  for (int i = blockIdx.x; i < N_ROWS; i += PAIR_BLOCKS) {
    float dpi = dp[i];                 // uniform across block
    if (dpi == -INFINITY) continue;    // wave-uniform skip of non-pos rows
    float dpi5 = dpi + MARGIN;
#pragma unroll
    for (int k = 0; k < N_ROWS / 256; ++k) acc += fmaxf(dpi5 - r[k], 0.f);
  }
#pragma unroll
  for (int off = 32; off; off >>= 1) acc += __shfl_down(acc, off, 64);
  __shared__ float ws[4];
  const int lane = threadIdx.x & 63, wid = threadIdx.x >> 6;
  if (lane == 0) ws[wid] = acc;
  __syncthreads();
  if (threadIdx.x == 0) partial[blockIdx.x] = ws[0] + ws[1] + ws[2] + ws[3];
}

// ---------------------------------------------------------------------------
// finalize: one block. Reduce 256 partials (in double), count positives from
// dp (dp[i] != -inf), write mean.
__global__ __launch_bounds__(256) void final_kernel(
    const float* __restrict__ dp, const float* __restrict__ partial,
    float* __restrict__ out) {
  double s = (double)partial[threadIdx.x];
  int c = 0;
#pragma unroll
  for (int k = 0; k < N_ROWS / 256; ++k)
    c += (dp[threadIdx.x + k * 256] != -INFINITY);
#pragma unroll
  for (int off = 32; off; off >>= 1) {
    s += __shfl_down(s, off, 64);
    c += __shfl_down(c, off, 64);
  }
  __shared__ double sws[4];
  __shared__ int cws[4];
  const int lane = threadIdx.x & 63, wid = threadIdx.x >> 6;
  if (lane == 0) { sws[wid] = s; cws[wid] = c; }
  __syncthreads();
  if (threadIdx.x == 0) {
    double tot = sws[0] + sws[1] + sws[2] + sws[3];
    long long np = cws[0] + cws[1] + cws[2] + cws[3];
    long long cnt = np * (long long)(N_ROWS - np);
    out[0] = (float)(tot / (double)cnt);
  }
}

// ---------------------------------------------------------------------------
extern "C" void kernel_launch(void* const* d_in, const int* in_sizes, int n_in,
                              void* d_out, int out_size, void* d_ws, size_t ws_size,
                              hipStream_t stream) {
  const float* rx  = (const float*)d_in[0];
  const float* x   = (const float*)d_in[1];
  const int*   tgt = (const int*)d_in[2];
  float* out = (float*)d_out;

  // ws layout: dp[8192] f32 | dn[8192] f32 | partial[256] f32
  float* dp      = (float*)d_ws;
  float* dn      = dp + N_ROWS;
  float* partial = dn + N_ROWS;

  dist_kernel<<<N_ROWS / 4, 256, 0, stream>>>(rx, x, tgt, dp, dn);
  pair_kernel<<<PAIR_BLOCKS, 256, 0, stream>>>(dp, dn, partial);
  final_kernel<<<1, 256, 0, stream>>>(dp, partial, out);
}

// Round 5
// 264.667 us; speedup vs baseline: 1.1914x; 1.0870x over previous
//
#include <hip/hip_runtime.h>
#include <math.h>

// Fixed shape: N=8192 rows, D=4096 cols, fp32 in, fp32 scalar out.
#define N_ROWS 8192
#define D_COLS 4096
#define MARGIN 5.0f
#define PAIR_BLOCKS 256

typedef float v4f __attribute__((ext_vector_type(4)));

// ---------------------------------------------------------------------------
// dist: one WAVE per row, 4 rows per 256-block, grid 2048.
// R1-R4 showed per-wave load scheduling is irrelevant: 98-102 us across four
// structures, isolated-profile FETCH=134 MB (rx from HBM, x from L3) at a
// combined 2.7 TB/s. This round's single change: NONTEMPORAL loads (nt flag)
// on both inputs to alter the L2/L3 allocation/miss path for streaming data.
// dp[i] = (t==1) ? d : -inf ; dn[i] = (t==0) ? d : +inf  (self-masking hinge).
__global__ __launch_bounds__(256) void dist_kernel(
    const float* __restrict__ rx, const float* __restrict__ x,
    const int* __restrict__ tgt, float* __restrict__ dp, float* __restrict__ dn) {
  const int lane = threadIdx.x & 63;
  const int row  = blockIdx.x * 4 + (threadIdx.x >> 6);
  const v4f* a = reinterpret_cast<const v4f*>(rx) + (size_t)row * (D_COLS / 4);
  const v4f* b = reinterpret_cast<const v4f*>(x)  + (size_t)row * (D_COLS / 4);
  float s0 = 0.f, s1 = 0.f, s2 = 0.f, s3 = 0.f;
#pragma unroll
  for (int k = 0; k < D_COLS / 4 / 64; ++k) {   // 16 float4 per lane per input
    v4f va = __builtin_nontemporal_load(&a[lane + k * 64]);
    v4f vb = __builtin_nontemporal_load(&b[lane + k * 64]);
    float d0 = va.x - vb.x, d1 = va.y - vb.y;
    float d2 = va.z - vb.z, d3 = va.w - vb.w;
    s0 = fmaf(d0, d0, s0); s1 = fmaf(d1, d1, s1);
    s2 = fmaf(d2, d2, s2); s3 = fmaf(d3, d3, s3);
  }
  float s = (s0 + s1) + (s2 + s3);
#pragma unroll
  for (int off = 32; off; off >>= 1) s += __shfl_down(s, off, 64);  // wave=64
  if (lane == 0) {
    float dd = sqrtf(s) + 0.001f;
    int t = tgt[row];
    dp[row] = (t == 1) ? dd : -INFINITY;
    dn[row] = (t == 0) ? dd : INFINITY;
  }
}

// ---------------------------------------------------------------------------
// pairs: NO atomics, NO fences. 256 blocks; each thread caches 32 dn values in
// registers; block strides over i (32 rows each); one f32 partial per block.
// The +-inf encoding zeroes masked pairs (no NaN possible: only -inf-(+inf)).
__global__ __launch_bounds__(256) void pair_kernel(
    const float* __restrict__ dp, const float* __restrict__ dn,
    float* __restrict__ partial) {
  float r[N_ROWS / 256];
#pragma unroll
  for (int k = 0; k < N_ROWS / 256; ++k) r[k] = dn[threadIdx.x + k * 256];
  float acc = 0.f;
#pragma unroll 1
  for (int i = blockIdx.x; i < N_ROWS; i += PAIR_BLOCKS) {
    float dpi = dp[i];                 // uniform across block
    if (dpi == -INFINITY) continue;    // wave-uniform skip of non-pos rows
    float dpi5 = dpi + MARGIN;
#pragma unroll
    for (int k = 0; k < N_ROWS / 256; ++k) acc += fmaxf(dpi5 - r[k], 0.f);
  }
#pragma unroll
  for (int off = 32; off; off >>= 1) acc += __shfl_down(acc, off, 64);
  __shared__ float ws[4];
  const int lane = threadIdx.x & 63, wid = threadIdx.x >> 6;
  if (lane == 0) ws[wid] = acc;
  __syncthreads();
  if (threadIdx.x == 0) partial[blockIdx.x] = ws[0] + ws[1] + ws[2] + ws[3];
}

// ---------------------------------------------------------------------------
// finalize: one block. Reduce 256 partials (in double), count positives from
// dp (dp[i] != -inf), write mean.
__global__ __launch_bounds__(256) void final_kernel(
    const float* __restrict__ dp, const float* __restrict__ partial,
    float* __restrict__ out) {
  double s = (double)partial[threadIdx.x];
  int c = 0;
#pragma unroll
  for (int k = 0; k < N_ROWS / 256; ++k)
    c += (dp[threadIdx.x + k * 256] != -INFINITY);
#pragma unroll
  for (int off = 32; off; off >>= 1) {
    s += __shfl_down(s, off, 64);
    c += __shfl_down(c, off, 64);
  }
  __shared__ double sws[4];
  __shared__ int cws[4];
  const int lane = threadIdx.x & 63, wid = threadIdx.x >> 6;
  if (lane == 0) { sws[wid] = s; cws[wid] = c; }
  __syncthreads();
  if (threadIdx.x == 0) {
    double tot = sws[0] + sws[1] + sws[2] + sws[3];
    long long np = cws[0] + cws[1] + cws[2] + cws[3];
    long long cnt = np * (long long)(N_ROWS - np);
    out[0] = (float)(tot / (double)cnt);
  }
}

// ---------------------------------------------------------------------------
extern "C" void kernel_launch(void* const* d_in, const int* in_sizes, int n_in,
                              void* d_out, int out_size, void* d_ws, size_t ws_size,
                              hipStream_t stream) {
  const float* rx  = (const float*)d_in[0];
  const float* x   = (const float*)d_in[1];
  const int*   tgt = (const int*)d_in[2];
  float* out = (float*)d_out;

  // ws layout: dp[8192] f32 | dn[8192] f32 | partial[256] f32
  float* dp      = (float*)d_ws;
  float* dn      = dp + N_ROWS;
  float* partial = dn + N_ROWS;

  dist_kernel<<<N_ROWS / 4, 256, 0, stream>>>(rx, x, tgt, dp, dn);
  pair_kernel<<<PAIR_BLOCKS, 256, 0, stream>>>(dp, dn, partial);
  final_kernel<<<1, 256, 0, stream>>>(dp, partial, out);
}

// Round 6
// 262.655 us; speedup vs baseline: 1.2006x; 1.0077x over previous
//
#include <hip/hip_runtime.h>
#include <math.h>

// Fixed shape: N=8192 rows, D=4096 cols, fp32 in, fp32 scalar out.
#define N_ROWS 8192
#define D_COLS 4096
#define MARGIN 5.0f
#define PAIR_BLOCKS 256

typedef float v4f __attribute__((ext_vector_type(4)));

// ---------------------------------------------------------------------------
// dist: one WAVE per row, 4 rows per 256-block, grid 2048.
// R6 structure: stage the ENTIRE a-row in registers (16 float4/lane = 64
// VGPRs), then stream the b-row with FMAs. The dataflow dependency forces all
// 16 a-loads live at once (compiler cannot sink them, unlike R3/R4), giving a
// guaranteed 16-deep load batch and two MONOTONE 16 KB streams per wave
// instead of R5's interleaved far-apart pairs. All loads nontemporal (R5's
// only win: 287->264 us total).
// dp[i] = (t==1) ? d : -inf ; dn[i] = (t==0) ? d : +inf  (self-masking hinge).
__global__ __launch_bounds__(256) void dist_kernel(
    const float* __restrict__ rx, const float* __restrict__ x,
    const int* __restrict__ tgt, float* __restrict__ dp, float* __restrict__ dn) {
  const int lane = threadIdx.x & 63;
  const int row  = blockIdx.x * 4 + (threadIdx.x >> 6);
  const v4f* a = reinterpret_cast<const v4f*>(rx) + (size_t)row * (D_COLS / 4);
  const v4f* b = reinterpret_cast<const v4f*>(x)  + (size_t)row * (D_COLS / 4);

  v4f ra[16];                                   // whole a-row: 64 VGPRs/lane
#pragma unroll
  for (int k = 0; k < 16; ++k) ra[k] = __builtin_nontemporal_load(&a[lane + k * 64]);

  float s0 = 0.f, s1 = 0.f, s2 = 0.f, s3 = 0.f;
#pragma unroll
  for (int k = 0; k < 16; ++k) {                // monotone b-stream + FMA
    v4f vb = __builtin_nontemporal_load(&b[lane + k * 64]);
    float d0 = ra[k].x - vb.x, d1 = ra[k].y - vb.y;
    float d2 = ra[k].z - vb.z, d3 = ra[k].w - vb.w;
    s0 = fmaf(d0, d0, s0); s1 = fmaf(d1, d1, s1);
    s2 = fmaf(d2, d2, s2); s3 = fmaf(d3, d3, s3);
  }
  float s = (s0 + s1) + (s2 + s3);
#pragma unroll
  for (int off = 32; off; off >>= 1) s += __shfl_down(s, off, 64);  // wave=64
  if (lane == 0) {
    float dd = sqrtf(s) + 0.001f;
    int t = tgt[row];
    dp[row] = (t == 1) ? dd : -INFINITY;
    dn[row] = (t == 0) ? dd : INFINITY;
  }
}

// ---------------------------------------------------------------------------
// pairs: NO atomics, NO fences. 256 blocks; each thread caches 32 dn values in
// registers; block strides over i (32 rows each); one f32 partial per block.
// The +-inf encoding zeroes masked pairs (no NaN possible: only -inf-(+inf)).
__global__ __launch_bounds__(256) void pair_kernel(
    const float* __restrict__ dp, const float* __restrict__ dn,
    float* __restrict__ partial) {
  float r[N_ROWS / 256];
#pragma unroll
  for (int k = 0; k < N_ROWS / 256; ++k) r[k] = dn[threadIdx.x + k * 256];
  float acc = 0.f;
#pragma unroll 1
  for (int i = blockIdx.x; i < N_ROWS; i += PAIR_BLOCKS) {
    float dpi = dp[i];                 // uniform across block
    if (dpi == -INFINITY) continue;    // wave-uniform skip of non-pos rows
    float dpi5 = dpi + MARGIN;
#pragma unroll
    for (int k = 0; k < N_ROWS / 256; ++k) acc += fmaxf(dpi5 - r[k], 0.f);
  }
#pragma unroll
  for (int off = 32; off; off >>= 1) acc += __shfl_down(acc, off, 64);
  __shared__ float ws[4];
  const int lane = threadIdx.x & 63, wid = threadIdx.x >> 6;
  if (lane == 0) ws[wid] = acc;
  __syncthreads();
  if (threadIdx.x == 0) partial[blockIdx.x] = ws[0] + ws[1] + ws[2] + ws[3];
}

// ---------------------------------------------------------------------------
// finalize: one block. Reduce 256 partials (in double), count positives from
// dp (dp[i] != -inf), write mean.
__global__ __launch_bounds__(256) void final_kernel(
    const float* __restrict__ dp, const float* __restrict__ partial,
    float* __restrict__ out) {
  double s = (double)partial[threadIdx.x];
  int c = 0;
#pragma unroll
  for (int k = 0; k < N_ROWS / 256; ++k)
    c += (dp[threadIdx.x + k * 256] != -INFINITY);
#pragma unroll
  for (int off = 32; off; off >>= 1) {
    s += __shfl_down(s, off, 64);
    c += __shfl_down(c, off, 64);
  }
  __shared__ double sws[4];
  __shared__ int cws[4];
  const int lane = threadIdx.x & 63, wid = threadIdx.x >> 6;
  if (lane == 0) { sws[wid] = s; cws[wid] = c; }
  __syncthreads();
  if (threadIdx.x == 0) {
    double tot = sws[0] + sws[1] + sws[2] + sws[3];
    long long np = cws[0] + cws[1] + cws[2] + cws[3];
    long long cnt = np * (long long)(N_ROWS - np);
    out[0] = (float)(tot / (double)cnt);
  }
}

// ---------------------------------------------------------------------------
extern "C" void kernel_launch(void* const* d_in, const int* in_sizes, int n_in,
                              void* d_out, int out_size, void* d_ws, size_t ws_size,
                              hipStream_t stream) {
  const float* rx  = (const float*)d_in[0];
  const float* x   = (const float*)d_in[1];
  const int*   tgt = (const int*)d_in[2];
  float* out = (float*)d_out;

  // ws layout: dp[8192] f32 | dn[8192] f32 | partial[256] f32
  float* dp      = (float*)d_ws;
  float* dn      = dp + N_ROWS;
  float* partial = dn + N_ROWS;

  dist_kernel<<<N_ROWS / 4, 256, 0, stream>>>(rx, x, tgt, dp, dn);
  pair_kernel<<<PAIR_BLOCKS, 256, 0, stream>>>(dp, dn, partial);
  final_kernel<<<1, 256, 0, stream>>>(dp, partial, out);
}